// Round 13
// baseline (444.780 us; speedup 1.0000x reference)
//
#include <hip/hip_runtime.h>

// Problem constants (B, L, H, D) = (4, 4096, 8, 64), FACTOR=5
#define NB 4
#define LSEQ 4096
#define NH 8
#define ND 64
#define NSAMP 45
#define NTOP 45
#define ACH 256            // keys per attention chunk
#define NCH (LSEQ / ACH)   // 16 chunks
#define SENT 0x7fffffff

typedef float f32x4 __attribute__((ext_vector_type(4)));

// ===========================================================================
// r18: compute_M occupancy WITHOUT spills + tail halving + fused merge.
// r13 forensics: launch_bounds(512,4) capped VGPR at 64 -> q spilled
// (WRITE_SIZE 6.6MB) -> its "more waves don't help" datum was invalid.
// New compute_M: 1024-thr blocks (cap 128 VGPR, q fits), parity split
// (fold = r13's validated sorted-order running (max,sum) -> M bit-identical
// to the passing r13 run), 512-row superchunks (8 phases, tail max ~8 vs
// 2x9), no Plds (LDS 147456: 1 blk/CU, 16 waves = 4/SIMD), pknext prefetch.
// attn_merge fused into cumsumCS (part in ws -> no clobber; per-chunk rows
// merged+scattered after own cumsum writes + __syncthreads; fence-free).
// 5 launches. Fallback tier: cumsumCS(noScatter) + attn_rows.
// ===========================================================================

// ---------------------------------------------------------------------------
// K1 fusedA: blocks 0..15 = prep (bucket-sort (idx,s) by 256-chunk, output
// split by sorted-position PARITY into two 24-int sentinel-terminated
// streams per l — r13 prep verbatim); blocks 16..527 = cumsumA.
// ---------------------------------------------------------------------------
__global__ __launch_bounds__(256) void fusedA_kernel(
        const int* __restrict__ idxS, int* __restrict__ sortedAB,
        const float* __restrict__ V, float* __restrict__ chunkSums) {
    int blk = blockIdx.x;
    int t = threadIdx.x;
    __shared__ int cnt[256][17];
    __shared__ float part[4][ND];

    if (blk < 16) {
        int l = blk * 256 + t;
        const int* is = idxS + (size_t)l * NSAMP;
        #pragma unroll
        for (int c = 0; c < 16; ++c) cnt[t][c] = 0;
        for (int s = 0; s < NSAMP; ++s) cnt[t][is[s] >> 8] += 1;
        int run = 0;
        #pragma unroll
        for (int c = 0; c < 16; ++c) { int v = cnt[t][c]; cnt[t][c] = run; run += v; }
        int* ab = sortedAB + (size_t)l * 48;
        ab[23] = SENT; ab[46] = SENT; ab[47] = SENT;
        for (int s = 0; s < NSAMP; ++s) {
            int idx = is[s];
            int p = cnt[t][idx >> 8]++;            // sorted position 0..44
            ab[(p & 1) * 24 + (p >> 1)] = (idx << 8) | s;
        }
    } else {
        int blk2 = blk - 16;
        int c = blk2 & 15;
        int bh = blk2 >> 4;
        int h = bh & (NH - 1);
        int b = bh >> 3;
        int g = t >> 6, d = t & 63;

        const size_t rstride = (size_t)NH * ND;
        size_t vbase = (size_t)b * LSEQ * rstride + (size_t)h * ND + d;

        int l0 = c * 256 + g * 64;
        float s = 0.0f;
        for (int l = l0; l < l0 + 64; ++l) s += V[vbase + (size_t)l * rstride];

        part[g][d] = s;
        __syncthreads();
        if (t < ND)
            chunkSums[(size_t)blk2 * ND + d] =
                part[0][d] + part[1][d] + part[2][d] + part[3][d];
    }
}

// ---------------------------------------------------------------------------
// K2 compute_M: 1024 threads (16 waves = 4/SIMD, 1 blk/CU), parity split
// (t<512: even sorted positions of l, t>=512: odd), 512-row superchunks
// (8 phases). Dot tree byte-identical; fold = running (max,sum) in sorted
// order per parity thread + LDS merge (max exact, sum fixed A,B order) —
// EXACTLY the r13 fold sequence (passed, absmax 1.0). XCD pinning kept
// (8 blocks/bh stage their bh's K -> 4MB L2 slice per XCD).
// ---------------------------------------------------------------------------
__global__ __launch_bounds__(1024, 1) void compute_M_kernel(
        const float* __restrict__ Q,
        const float* __restrict__ K,
        const int* __restrict__ sortedAB,
        float* __restrict__ Mout) {
    int xcd = blockIdx.x & 7;
    int sub = blockIdx.x >> 3;             // 0..31
    int bh  = (xcd << 2) | (sub & 3);      // 4 bh per XCD
    int lt  = sub >> 2;                    // 0..7 (512-l tile)
    int b = bh >> 3, h = bh & 7;
    int t = threadIdx.x;                   // 0..1023
    int lloc = t & 511;
    int par  = t >> 9;                     // 0: even positions, 1: odd
    int l = (lt << 9) | lloc;

    __shared__ float Ks[512 * 68];         // 139264 B
    __shared__ float redM[1024];
    __shared__ float redS[1024];

    // Q row in regs (nontemporal: one-shot stream, keep L2 for K).
    f32x4 qa[16];
    {
        const f32x4* qp = reinterpret_cast<const f32x4*>(
            Q + (((size_t)b * LSEQ + l) * NH + h) * ND);
        #pragma unroll
        for (int i = 0; i < 16; ++i) qa[i] = __builtin_nontemporal_load(qp + i);
    }

    // EXACT original per-dot tree: products, off=32 fused, then 16/8/4/2/1.
    auto dotQK = [&](const f32x4 (&q4)[16], const float* kr) -> float {
        const f32x4* k4 = reinterpret_cast<const f32x4*>(kr);
        float w[32];
        #pragma unroll
        for (int i = 0; i < 8; ++i) {
            f32x4 a = q4[i], bb = k4[i], c = q4[i + 8], d4 = k4[i + 8];
            w[4 * i + 0] = __fadd_rn(__fmul_rn(a.x, bb.x), __fmul_rn(c.x, d4.x));
            w[4 * i + 1] = __fadd_rn(__fmul_rn(a.y, bb.y), __fmul_rn(c.y, d4.y));
            w[4 * i + 2] = __fadd_rn(__fmul_rn(a.z, bb.z), __fmul_rn(c.z, d4.z));
            w[4 * i + 3] = __fadd_rn(__fmul_rn(a.w, bb.w), __fmul_rn(c.w, d4.w));
        }
        #pragma unroll
        for (int off = 16; off; off >>= 1) {
            #pragma unroll
            for (int i = 0; i < off; ++i) w[i] = __fadd_rn(w[i], w[i + off]);
        }
        return w[0];
    };

    // Parity stream walk with one-ahead prefetch (takes the sortedAB load
    // off the serial critical path). Reads beyond the sentinel stay inside
    // this l's 48-int slot; values are never consumed past the sentinel.
    const int* sp = sortedAB + (size_t)l * 48 + par * 24;
    int ptr = 1;
    int pk = sp[0];
    int pknext = sp[1];

    size_t kbh = ((size_t)b * LSEQ * NH + h) * ND;

    float maxv = -INFINITY;
    float sumv = 0.0f;

    for (int c2 = 0; c2 < 8; ++c2) {
        // stage rows [c2*512, c2*512+512): 8192 f32x4 over 1024 thr = 8 ea.
        #pragma unroll
        for (int i = 0; i < 8; ++i) {
            int flat = i * 1024 + t;
            int row = flat >> 4, col = flat & 15;
            f32x4 v = *reinterpret_cast<const f32x4*>(
                K + kbh + (size_t)(c2 * 512 + row) * (NH * ND) + col * 4);
            *reinterpret_cast<f32x4*>(&Ks[row * 68 + col * 4]) = v;
        }
        __syncthreads();

        while ((pk >> 17) == c2) {           // superchunk = global row >> 9
            int r = (pk >> 8) & 511;         // row within superchunk
            ++ptr;
            int pk2 = sp[ptr];               // prefetch two-ahead
            float p = dotQK(qa, &Ks[r * 68]);
            maxv = fmaxf(maxv, p);
            sumv = __fadd_rn(sumv, p);
            pk = pknext;
            pknext = pk2;
        }
        __syncthreads();
    }

    // merge parity halves: max exact; sum in fixed (A,B) order (r13 fold).
    redM[t] = maxv; redS[t] = sumv;
    __syncthreads();
    if (t < 512) {
        float m = fmaxf(redM[t], redM[t + 512]);
        float s = __fadd_rn(redS[t], redS[t + 512]);
        Mout[(size_t)bh * LSEQ + ((lt << 9) | t)] = m - s * (1.0f / (float)LSEQ);
    }
}

// ---------------------------------------------------------------------------
// K3 topk: top-45 per (b,h). UNCHANGED (selection semantics frozen).
// ---------------------------------------------------------------------------
__global__ __launch_bounds__(256) void topk_kernel(
        const float* __restrict__ M, int* __restrict__ Mtop) {
    int bh = blockIdx.x;
    int t = threadIdx.x;
    int wave = t >> 6, lane = t & 63;
    const float* m = M + (size_t)bh * LSEQ;

    float rv[16];
    #pragma unroll
    for (int k = 0; k < 16; ++k) rv[k] = m[t + (k << 8)];

    __shared__ float wv[4];
    __shared__ int   wi[4];
    __shared__ int   winIdx;

    for (int iter = 0; iter < NTOP; ++iter) {
        float bv = -INFINITY; int bi = 0x7fffffff;
        #pragma unroll
        for (int k = 0; k < 16; ++k) {
            float v = rv[k];
            if (v > bv) { bv = v; bi = t + (k << 8); }
        }
        #pragma unroll
        for (int off = 1; off < 64; off <<= 1) {
            float ov = __shfl_xor(bv, off, 64);
            int   oi = __shfl_xor(bi, off, 64);
            if (ov > bv || (ov == bv && oi < bi)) { bv = ov; bi = oi; }
        }
        if (lane == 0) { wv[wave] = bv; wi[wave] = bi; }
        __syncthreads();
        if (t == 0) {
            float cv = wv[0]; int ci = wi[0];
            for (int ww = 1; ww < 4; ++ww) {
                if (wv[ww] > cv || (wv[ww] == cv && wi[ww] < ci)) { cv = wv[ww]; ci = wi[ww]; }
            }
            winIdx = ci;
            Mtop[bh * NTOP + iter] = ci;
        }
        __syncthreads();
        int widx = winIdx;
        #pragma unroll
        for (int k = 0; k < 16; ++k)
            if (widx == t + (k << 8)) rv[k] = -INFINITY;
        __syncthreads();
    }
}

// ---------------------------------------------------------------------------
// K4 attn_partial: flash split-K attention (r11 body). UNCHANGED except
// part now lives in ws (same pointer type).
// ---------------------------------------------------------------------------
__global__ __launch_bounds__(256, 1) void attn_partial_kernel(
        const float* __restrict__ Q, const float* __restrict__ K,
        const float* __restrict__ V, const int* __restrict__ Mtop,
        float* __restrict__ part) {
    int bh = blockIdx.x >> 4;
    int c  = blockIdx.x & 15;
    int b = bh >> 3, h = bh & 7;
    int t = threadIdx.x;
    int w = t >> 6, lane = t & 63;
    int jj = lane >> 4, dq = lane & 15;

    __shared__ float Qs[NTOP * ND];
    __shared__ int   posS[NTOP];
    __shared__ float Vs[64][68];
    __shared__ float Pw[4][64];

    size_t base = ((size_t)b * LSEQ * NH + h) * ND;

    if (t < NTOP) posS[t] = Mtop[bh * NTOP + t];
    __syncthreads();
    for (int idx = t; idx < NTOP * 16; idx += 256) {
        int u = idx >> 4, cg = idx & 15;
        f32x4 v = *reinterpret_cast<const f32x4*>(
            Q + base + (size_t)posS[u] * (NH * ND) + cg * 4);
        *reinterpret_cast<f32x4*>(&Qs[u * ND + cg * 4]) = v;
    }

    f32x4 o[12];
    float mreg[12], sreg[12];
    #pragma unroll
    for (int qi = 0; qi < 12; ++qi) {
        o[qi] = 0.0f; mreg[qi] = -INFINITY; sreg[qi] = 0.0f;
    }

    for (int tt = 0; tt < ACH / 64; ++tt) {
        int tile0 = c * ACH + tt * 64;
        __syncthreads();
        #pragma unroll
        for (int i = 0; i < 4; ++i) {
            int flat = i * 256 + t;
            int r = flat >> 4, cg = flat & 15;
            f32x4 v = *reinterpret_cast<const f32x4*>(
                V + base + (size_t)(tile0 + r) * (NH * ND) + cg * 4);
            *reinterpret_cast<f32x4*>(&Vs[r][cg * 4]) = v;
        }
        __syncthreads();

        f32x4 kreg[16];
        #pragma unroll
        for (int i = 0; i < 16; ++i)
            kreg[i] = *reinterpret_cast<const f32x4*>(
                K + base + (size_t)(tile0 + lane) * (NH * ND) + i * 4);

        #pragma unroll
        for (int qi = 0; qi < 12; ++qi) {
            int u = w + 4 * qi;
            if (u >= NTOP) continue;
            int pu = posS[u];
            if (pu < tile0) continue;

            float a0 = 0, a1 = 0, a2 = 0, a3 = 0;
            #pragma unroll
            for (int di = 0; di < 16; ++di) {
                f32x4 qv = *reinterpret_cast<const f32x4*>(&Qs[u * ND + di * 4]);
                a0 = fmaf(qv.x, kreg[di].x, a0);
                a1 = fmaf(qv.y, kreg[di].y, a1);
                a2 = fmaf(qv.z, kreg[di].z, a2);
                a3 = fmaf(qv.w, kreg[di].w, a3);
            }
            float sc = ((a0 + a1) + (a2 + a3)) * 0.125f;
            if (tile0 + lane > pu) sc = -INFINITY;

            float tmax = sc;
            #pragma unroll
            for (int off = 1; off < 64; off <<= 1)
                tmax = fmaxf(tmax, __shfl_xor(tmax, off, 64));
            float mold = mreg[qi];
            float mnew = fmaxf(mold, tmax);
            float alpha = __expf(mold - mnew);
            float e = __expf(sc - mnew);
            float esum = e;
            #pragma unroll
            for (int off = 1; off < 64; off <<= 1)
                esum += __shfl_xor(esum, off, 64);
            sreg[qi] = sreg[qi] * alpha + esum;
            mreg[qi] = mnew;
            Pw[w][lane] = e;
            o[qi] *= alpha;
            #pragma unroll
            for (int i = 0; i < 16; ++i) {
                float pe = Pw[w][i * 4 + jj];
                f32x4 vv = *reinterpret_cast<const f32x4*>(&Vs[i * 4 + jj][dq * 4]);
                o[qi] += vv * pe;
            }
        }
    }

    #pragma unroll
    for (int qi = 0; qi < 12; ++qi) {
        int u = w + 4 * qi;
        if (u >= NTOP) continue;
        if (posS[u] < c * ACH) continue;
        f32x4 oo = o[qi];
        #pragma unroll
        for (int off = 16; off <= 32; off <<= 1) {
            oo.x += __shfl_xor(oo.x, off, 64);
            oo.y += __shfl_xor(oo.y, off, 64);
            oo.z += __shfl_xor(oo.z, off, 64);
            oo.w += __shfl_xor(oo.w, off, 64);
        }
        size_t pb = ((size_t)(bh * NTOP + u) * NCH + c) * 72;
        if (lane < 16)
            *reinterpret_cast<f32x4*>(&part[pb + 4 + dq * 4]) = oo;
        if (lane == 0) { part[pb] = mreg[qi]; part[pb + 1] = sreg[qi]; }
    }
}

// ---------------------------------------------------------------------------
// K5 cumsumCS: rescan chunk with exclusive prefix, write out; then
// (doScatter) MERGE+SCATTER the attention rows whose pos is in THIS chunk:
// wave w merges rows u=w,w+4,.. from part (complete: attn_partial is a
// previous launch) and overwrites out[pos] — after this block's own cumsum
// writes + __syncthreads(), so no fence needed. part lives in ws, so
// cumsum writes to out (d_out) cannot clobber it.
// ---------------------------------------------------------------------------
__global__ __launch_bounds__(256) void cumsumCS_kernel(
        const float* __restrict__ V, const float* __restrict__ chunkSums,
        const int* __restrict__ Mtop, const float* __restrict__ part,
        float* __restrict__ out, int doScatter) {
    int blk = blockIdx.x;
    int c = blk & 15;
    int bh = blk >> 4;
    int h = bh & (NH - 1);
    int b = bh >> 3;
    int g = threadIdx.x >> 6, d = threadIdx.x & 63;
    int t = threadIdx.x;

    const size_t rstride = (size_t)NH * ND;
    size_t vbase = (size_t)b * LSEQ * rstride + (size_t)h * ND + d;

    float run = 0.0f;
    for (int cc = 0; cc < c; ++cc)
        run += chunkSums[((size_t)bh * 16 + cc) * ND + d];

    int l0 = c * 256 + g * 64;
    float s = 0.0f;
    for (int l = l0; l < l0 + 64; ++l) s += V[vbase + (size_t)l * rstride];
    __shared__ float cpart[4][ND];
    cpart[g][d] = s;
    __syncthreads();
    for (int gg = 0; gg < g; ++gg) run += cpart[gg][d];

    size_t obase = (size_t)bh * LSEQ * ND + d;
    for (int l = l0; l < l0 + 64; ++l) {
        run += V[vbase + (size_t)l * rstride];
        out[obase + (size_t)l * ND] = run;
    }

    if (!doScatter) return;
    __syncthreads();   // this block's cumsum writes drained before overwrite
    int w = t >> 6, lane = t & 63;
    for (int u = w; u < NTOP; u += 4) {
        int pos = Mtop[bh * NTOP + u];
        if ((pos >> 8) != c) continue;
        size_t pb0 = (size_t)(bh * NTOP + u) * NCH * 72;
        float mm = -INFINITY;
        for (int cc = 0; cc <= c; ++cc)
            mm = fmaxf(mm, part[pb0 + (size_t)cc * 72]);
        float S = 0.0f, oacc = 0.0f;
        for (int cc = 0; cc <= c; ++cc) {
            float mc = part[pb0 + (size_t)cc * 72];
            float sc = part[pb0 + (size_t)cc * 72 + 1];
            float wgt = __expf(mc - mm);
            S = fmaf(sc, wgt, S);
            oacc = fmaf(part[pb0 + (size_t)cc * 72 + 4 + lane], wgt, oacc);
        }
        out[((size_t)bh * LSEQ + pos) * ND + lane] = oacc / S;
    }
}

// ---------------------------------------------------------------------------
// Fallback: per-(bh,u) flash attention (r6). Used only if ws too small.
// ---------------------------------------------------------------------------
#define TJ 64
__global__ __launch_bounds__(256) void attn_rows_kernel(
        const float* __restrict__ Q,
        const float* __restrict__ K,
        const float* __restrict__ V,
        const int* __restrict__ Mtop,
        float* __restrict__ out) {
    int x = blockIdx.x;
    int xcd = x & 7;
    int slot = x >> 3;
    int grp = slot / NTOP;
    int u = slot % NTOP;
    int bh = grp * 8 + xcd;
    int h = bh & (NH - 1);
    int b = bh >> 3;
    int pos = Mtop[bh * NTOP + u];
    int n = pos + 1;
    int t = threadIdx.x;
    int r = t >> 2, qt = t & 3;

    __shared__ float Ks[TJ][65];
    __shared__ float Vs[TJ][65];
    __shared__ float red[256];

    const size_t rstride = (size_t)NH * ND;
    size_t base = (size_t)b * LSEQ * rstride + (size_t)h * ND;

    float qreg[16];
    const float* qrow = Q + base + (size_t)pos * rstride + qt * 16;
    #pragma unroll
    for (int i = 0; i < 16; i += 4) {
        float4 v4 = *reinterpret_cast<const float4*>(qrow + i);
        qreg[i] = v4.x; qreg[i + 1] = v4.y; qreg[i + 2] = v4.z; qreg[i + 3] = v4.w;
    }

    float m = -INFINITY, s = 0.0f;
    float o[16];
    #pragma unroll
    for (int dd = 0; dd < 16; ++dd) o[dd] = 0.0f;

    int ntiles = (n + TJ - 1) / TJ;
    for (int tt = 0; tt < ntiles; ++tt) {
        int j0 = tt * TJ;
        __syncthreads();
        #pragma unroll
        for (int i = 0; i < 4; ++i) {
            int u16 = t + i * 256;
            int rr = u16 >> 4, cc = u16 & 15;
            int j = j0 + rr;
            int jc = (j < n) ? j : (n - 1);
            const float* rowk = K + base + (size_t)jc * rstride;
            float4 kv = *reinterpret_cast<const float4*>(rowk + cc * 4);
            Ks[rr][cc * 4 + 0] = kv.x; Ks[rr][cc * 4 + 1] = kv.y;
            Ks[rr][cc * 4 + 2] = kv.z; Ks[rr][cc * 4 + 3] = kv.w;
            const float* rowv = V + base + (size_t)jc * rstride;
            float4 vv = *reinterpret_cast<const float4*>(rowv + cc * 4);
            Vs[rr][cc * 4 + 0] = vv.x; Vs[rr][cc * 4 + 1] = vv.y;
            Vs[rr][cc * 4 + 2] = vv.z; Vs[rr][cc * 4 + 3] = vv.w;
        }
        __syncthreads();

        int j = j0 + r;
        float acc = 0.0f;
        #pragma unroll
        for (int dd = 0; dd < 16; ++dd)
            acc = fmaf(qreg[dd], Ks[r][qt * 16 + dd], acc);
        acc += __shfl_xor(acc, 1, 64);
        acc += __shfl_xor(acc, 2, 64);

        if (j < n) {
            float sc = acc * 0.125f;
            if (sc > m) {
                float alpha = __expf(m - sc);
                s *= alpha;
                #pragma unroll
                for (int dd = 0; dd < 16; ++dd) o[dd] *= alpha;
                m = sc;
            }
            float e = __expf(sc - m);
            s += e;
            #pragma unroll
            for (int dd = 0; dd < 16; ++dd)
                o[dd] = fmaf(e, Vs[r][qt * 16 + dd], o[dd]);
        }
    }
    __syncthreads();

    red[t] = m; __syncthreads();
    for (int sft = 128; sft; sft >>= 1) {
        if (t < sft) red[t] = fmaxf(red[t], red[t + sft]);
        __syncthreads();
    }
    float mstar = red[0]; __syncthreads();
    float a = __expf(m - mstar);

    red[t] = s * a; __syncthreads();
    for (int sft = 128; sft; sft >>= 1) {
        if (t < sft) red[t] += red[t + sft];
        __syncthreads();
    }
    float S = red[0]; __syncthreads();

    float* OB = &Ks[0][0];
    #pragma unroll
    for (int dd = 0; dd < 16; ++dd) OB[t * 16 + dd] = o[dd] * a;
    __syncthreads();

    if (t < ND) {
        int qtt = t >> 4, dd = t & 15;
        float tot = 0.0f;
        for (int k = 0; k < 64; ++k) tot += OB[(4 * k + qtt) * 16 + dd];
        out[((size_t)bh * LSEQ + pos) * ND + t] = tot / S;
    }
}

// ---------------------------------------------------------------------------
extern "C" void kernel_launch(void* const* d_in, const int* in_sizes, int n_in,
                              void* d_out, int out_size, void* d_ws, size_t ws_size,
                              hipStream_t stream) {
    const float* Q = (const float*)d_in[0];
    const float* K = (const float*)d_in[1];
    const float* V = (const float*)d_in[2];
    const int* idxS = (const int*)d_in[3];
    float* out = (float*)d_out;

    // d_out scratch (consumed before cumsumCS writes out):
    //   M        @ 0     (512 KB)  -> topk
    //   sortedAB @ 1 MB  (768 KB)  -> compute_M
    // ws: Mtop (5760B) @0, chunkSums (128KB) @8192, part (6.6MB) @139264.
    float* Mbuf = (float*)d_out;
    int*   sortedAB = (int*)((char*)d_out + (1 << 20));
    int*   Mtop = (int*)d_ws;
    float* chunkSums = (float*)((char*)d_ws + 8192);
    float* part = (float*)((char*)d_ws + 139264);
    size_t wsNeed = 139264 + (size_t)NB * NH * NTOP * NCH * 72 * 4;

    fusedA_kernel<<<528, 256, 0, stream>>>(idxS, sortedAB, V, chunkSums);
    compute_M_kernel<<<256, 1024, 0, stream>>>(Q, K, sortedAB, Mbuf);
    topk_kernel<<<NB * NH, 256, 0, stream>>>(Mbuf, Mtop);

    if (ws_size >= wsNeed) {
        attn_partial_kernel<<<NB * NH * NCH, 256, 0, stream>>>(Q, K, V, Mtop, part);
        cumsumCS_kernel<<<NB * NH * 16, 256, 0, stream>>>(V, chunkSums, Mtop, part, out, 1);
    } else {
        cumsumCS_kernel<<<NB * NH * 16, 256, 0, stream>>>(V, chunkSums, Mtop, part, out, 0);
        attn_rows_kernel<<<NB * NH * NTOP, 256, 0, stream>>>(Q, K, V, Mtop, out);
    }
}